// Round 10
// baseline (449.962 us; speedup 1.0000x reference)
//
#include <hip/hip_runtime.h>

#define N_NODES 50000
#define N_EDGES 400000
#define E_TOT   450000   // + self loops
#define NEG 0.2f
#define NB_SCAN ((N_NODES + 255) / 256)   // 196 blocks
#define MAXD 64                            // LDS-cached edges per node (P(deg>64) ~ 0)
#define NG0 196                            // gemm0fs blocks (256 rows each; <= 256 CUs = 1 round)
#define EPB ((E_TOT + NG0 - 1) / NG0)      // edges scattered per gemm0fs block

typedef unsigned short ushort_t;
typedef __attribute__((ext_vector_type(8))) _Float16 half8;  // MFMA A/B frag (4 VGPRs)
typedef __attribute__((ext_vector_type(4))) float  f32x4;    // MFMA C/D frag
typedef __attribute__((ext_vector_type(8))) unsigned short ushort8;

__device__ __forceinline__ ushort_t f2h(float f){
    _Float16 h = (_Float16)f;
    union { _Float16 h; ushort_t u; } v; v.h = h; return v.u;
}
__device__ __forceinline__ float h_lo(unsigned u){
    union { unsigned u; _Float16 h[2]; } v; v.u = u; return (float)v.h[0];
}
__device__ __forceinline__ float h_hi(unsigned u){
    union { unsigned u; _Float16 h[2]; } v; v.u = u; return (float)v.h[1];
}
__device__ __forceinline__ void gload_lds16(const void* g, void* l){
    __builtin_amdgcn_global_load_lds((const __attribute__((address_space(1))) void*)g,
                                     (__attribute__((address_space(3))) void*)l, 16, 0, 0);
}
__device__ __forceinline__ int wave_incl_scan(int v, int lane){
    #pragma unroll
    for(int off = 1; off < 64; off <<= 1){
        int t = __shfl_up(v, off, 64);
        if(lane >= off) v += t;
    }
    return v;
}

// ---------------- fused fp32 -> f16 weight conversions + degree count ----------------
// requires deg (=wofs) pre-zeroed via hipMemsetAsync.  x is staged directly by gemm0fs.

__global__ void cvt_all(const float* __restrict__ W0,
                        const float* __restrict__ W1, const float* __restrict__ W2,
                        const int* __restrict__ ei,
                        ushort_t* __restrict__ W0t,
                        ushort_t* __restrict__ W1t, ushort_t* __restrict__ W2t,
                        int* __restrict__ deg){
    int i = blockIdx.x*256 + threadIdx.x;
    if(i < 512*128){ int n = i >> 7, k = i & 127; W0t[i] = f2h(W0[(size_t)k*512 + n]); }
    if(i < 512*512){ int n = i >> 9, k = i & 511; W1t[i] = f2h(W1[(size_t)k*512 + n]); }
    if(i < 16*512){ int n = i >> 9, k = i & 511; W2t[i] = f2h(W2[(size_t)k*16 + n]); }
    if(i < E_TOT){
        int dst = (i < N_EDGES) ? ei[N_EDGES + i] : (i - N_EDGES);
        atomicAdd(&deg[dst], 1);
    }
}

// ---------------- ordered CSR build: block sums -> fused scan+apply ----------------

__global__ void deg_block_sum(const int* __restrict__ deg, int* __restrict__ bsum){
    int i = blockIdx.x*256 + threadIdx.x;
    int lane = threadIdx.x & 63, wave = threadIdx.x >> 6;
    int v = (i < N_NODES) ? deg[i] : 0;
    #pragma unroll
    for(int off = 1; off < 64; off <<= 1) v += __shfl_xor(v, off, 64);
    __shared__ int sw[4];
    if(lane == 0) sw[wave] = v;
    __syncthreads();
    if(threadIdx.x == 0) bsum[blockIdx.x] = sw[0] + sw[1] + sw[2] + sw[3];
}

__global__ void scan_apply(const int* __restrict__ bsum,
                           int* __restrict__ dw, int* __restrict__ rowptr){
    __shared__ int soff;
    __shared__ int sw[4];
    int i = blockIdx.x*256 + threadIdx.x;
    int lane = threadIdx.x & 63, wave = threadIdx.x >> 6;
    if(wave == 0){
        int s = 0;
        for(int j = lane; j < (int)blockIdx.x; j += 64) s += bsum[j];
        #pragma unroll
        for(int off = 1; off < 64; off <<= 1) s += __shfl_xor(s, off, 64);
        if(lane == 0) soff = s;
    }
    int v = (i < N_NODES) ? dw[i] : 0;
    int incl = wave_incl_scan(v, lane);
    if(lane == 63) sw[wave] = incl;
    __syncthreads();
    int add = soff;
    for(int w = 0; w < wave; w++) add += sw[w];
    int excl = incl - v + add;
    if(i < N_NODES){ rowptr[i] = excl; dw[i] = excl; }
    if(i == N_NODES-1) rowptr[N_NODES] = excl + v;
}

// ---------------- layer-0 GEMM + fused edge scatter (round-9 proven form) ----------------

__global__ __launch_bounds__(512, 1) void gemm0fs(const int* __restrict__ ei,
                                                  int* __restrict__ wofs,
                                                  int* __restrict__ csr,
                                                  const float* __restrict__ x,
                                                  const ushort_t* __restrict__ W0t,
                                                  ushort_t* __restrict__ Cb,
                                                  const float* __restrict__ a_s,
                                                  const float* __restrict__ a_d,
                                                  float* __restrict__ als,
                                                  float* __restrict__ ald, int M){
    extern __shared__ ushort_t lds[];        // Bs: [0,65536) halves, As: [65536,81920)
    ushort_t* Bs = lds;
    ushort_t* As = lds + 512*128;
    int tid = threadIdx.x, wave = tid >> 6, lane = tid & 63;
    int rsub = lane >> 4, c16 = lane & 15;
    int fm = lane & 15, fq = lane >> 4;
    long row0 = (long)blockIdx.x * 256;

    auto stageA = [&](long base){
        #pragma unroll
        for(int t = 0; t < 4; t++){
            int rl = wave*16 + t*4 + rsub;         // local row 0..127
            long gr = base + rl; gr = gr < M ? gr : M-1;
            const float* ap = x + gr*128 + c16*8;
            f32x4 lo = *(const f32x4*)ap;
            f32x4 hi = *(const f32x4*)(ap + 4);
            union { _Float16 h[8]; half8 v; } u;
            u.h[0] = (_Float16)lo[0]; u.h[1] = (_Float16)lo[1];
            u.h[2] = (_Float16)lo[2]; u.h[3] = (_Float16)lo[3];
            u.h[4] = (_Float16)hi[0]; u.h[5] = (_Float16)hi[1];
            u.h[6] = (_Float16)hi[2]; u.h[7] = (_Float16)hi[3];
            *(half8*)&As[(size_t)rl*128 + (c16 ^ (rl & 7))*8] = u.v;
        }
    };
    auto compute = [&](f32x4 (&acc)[8][4]){
        #pragma unroll
        for(int kt = 0; kt < 4; kt++){
            half8 a[8], b[4];
            #pragma unroll
            for(int mi = 0; mi < 8; mi++){
                int r = mi*16 + fm;
                a[mi] = *(const half8*)&As[(size_t)r*128 + ((kt*4 + fq) ^ (r & 7))*8];
            }
            #pragma unroll
            for(int nj = 0; nj < 4; nj++){
                int r = wave*64 + nj*16 + fm;
                b[nj] = *(const half8*)&Bs[(size_t)r*128 + ((kt*4 + fq) ^ (r & 7))*8];
            }
            #pragma unroll
            for(int mi = 0; mi < 8; mi++)
                #pragma unroll
                for(int nj = 0; nj < 4; nj++)
                    acc[mi][nj] = __builtin_amdgcn_mfma_f32_16x16x32_f16(a[mi], b[nj], acc[mi][nj], 0, 0, 0);
        }
    };
    auto epilogue = [&](f32x4 (&acc)[8][4], long base){
        int head = wave;
        float asv[4], adv[4];
        #pragma unroll
        for(int nj = 0; nj < 4; nj++){
            int c = head*64 + nj*16 + fm;
            asv[nj] = a_s[c]; adv[nj] = a_d[c];
        }
        #pragma unroll
        for(int mi = 0; mi < 8; mi++){
            #pragma unroll
            for(int p2 = 0; p2 < 4; p2++){
                long r = base + mi*16 + fq*4 + p2;
                float ps = 0.f, pd = 0.f;
                if(r < M){
                    ushort_t* cp = &Cb[(size_t)r*512 + head*64 + fm];
                    #pragma unroll
                    for(int nj = 0; nj < 4; nj++){
                        float v = acc[mi][nj][p2];
                        cp[nj*16] = f2h(v);
                        ps += v*asv[nj]; pd += v*adv[nj];
                    }
                }
                #pragma unroll
                for(int off = 1; off < 16; off <<= 1){
                    ps += __shfl_xor(ps, off);
                    pd += __shfl_xor(pd, off);
                }
                if(fm == 0 && r < M){ als[r*8 + head] = ps; ald[r*8 + head] = pd; }
            }
        }
    };

    // ---- stage B (whole W0t) + A tile 0 ----
    #pragma unroll
    for(int s = 0; s < 16; s++){
        int rowq = wave*64 + s*4;
        int r = rowq + rsub;
        int sc = c16 ^ (r & 7);
        gload_lds16(W0t + (size_t)r*128 + sc*8, Bs + rowq*128);
    }
    stageA(row0);

    // ---- CSR scatter slice: independent work hiding under staging latency ----
    {
        int e1 = blockIdx.x*EPB + EPB; if(e1 > E_TOT) e1 = E_TOT;
        for(int e = blockIdx.x*EPB + tid; e < e1; e += 512){
            int src, dst;
            if(e < N_EDGES){ src = ei[e]; dst = ei[N_EDGES + e]; }
            else { src = dst = e - N_EDGES; }
            int pos = atomicAdd(&wofs[dst], 1);
            csr[pos] = src;
        }
    }

    __syncthreads();   // drains B gloads + A ds_writes (+ scatter)

    f32x4 acc[8][4] = {};
    compute(acc);
    __syncthreads();            // all waves done reading As (tile 0)
    stageA(row0 + 128);         // tile-1 A-stage issued early...
    epilogue(acc, row0);        // ...hides under tile-0 epilogue stores
    __syncthreads();            // tile-1 As visible

    f32x4 acc2[8][4] = {};
    compute(acc2);
    epilogue(acc2, row0 + 128);
}

// ---------------- layer-1 GEMM: 256x256 tile, BK=64, 8 waves, pipelined + XCD swizzle ----------------
// T4 counted-vmcnt (round-8 proven form).

template<int K>
__global__ __launch_bounds__(512, 2) void gemm_bt8(const ushort_t* __restrict__ A,
                                                   const ushort_t* __restrict__ Bt,
                                                   ushort_t* __restrict__ Cb,
                                                   const float* __restrict__ a_s,
                                                   const float* __restrict__ a_d,
                                                   float* __restrict__ als,
                                                   float* __restrict__ ald, int M){
    extern __shared__ ushort_t lds[];   // As[2]:[0,32768) halves, Bs[2]:[32768,65536) halves = 128 KiB
    constexpr int NT = K / 64;
    int tid = threadIdx.x, wave = tid >> 6, lane = tid & 63;
    int wm = wave >> 2, wn = wave & 3;          // 2M x 4N waves, per-wave C = 128x64

    // bijective XCD remap: both column-halves of a 256-row panel on the same XCD
    int s = blockIdx.x, nb = gridDim.x;
    int cc = s & 7, kk = s >> 3;
    int q = nb >> 3, rr = nb & 7;
    int t = (cc < rr ? cc*(q+1) : rr*(q+1) + (cc-rr)*q) + kk;
    int row0 = (t >> 1) * 256;
    int col0 = (t & 1) * 256;

    int lr = lane >> 3;                 // 0..7
    int cs8 = ((lane & 7) ^ lr) << 3;   // pre-swizzled 8-half chunk offset in source row
    int arows[4], brows[4];
    #pragma unroll
    for(int i = 0; i < 4; i++){
        int r = row0 + (wave << 5) + (i << 3) + lr;
        arows[i] = r < M ? r : M-1;
        brows[i] = col0 + (wave << 5) + (i << 3) + lr;
    }

    int l15 = lane & 15, fq = lane >> 4;
    int xr = (lane & 7) << 4;
    int xco0 = ((fq << 4)      ) ^ xr;  // kstep 0 byte offset within row (swizzled)
    int xco1 = (64 | (fq << 4)) ^ xr;   // kstep 1

    f32x4 acc[8][4] = {};

    auto stage = [&](int nbuf, int kt, int i){
        ushort_t* la = lds + nbuf*16384 + (wave << 11) + (i << 9);
        ushort_t* lb = lds + 32768 + nbuf*16384 + (wave << 11) + (i << 9);
        gload_lds16(A  + (size_t)arows[i]*K + kt + cs8, la);
        gload_lds16(Bt + (size_t)brows[i]*K + kt + cs8, lb);
    };

    // prologue: tile 0 -> buf 0, tile 1 -> buf 1 (16 loads in flight)
    #pragma unroll
    for(int i = 0; i < 4; i++) stage(0, 0, i);
    #pragma unroll
    for(int i = 0; i < 4; i++) stage(1, 64, i);

    for(int it = 0; it < NT; ++it){
        int b = it & 1;
        if(it < NT-1) asm volatile("s_waitcnt vmcnt(8)" ::: "memory");  // tile it done, it+1 in flight
        else         asm volatile("s_waitcnt vmcnt(0)" ::: "memory");
        __builtin_amdgcn_s_barrier();
        const char* Ac = (const char*)(lds + b*16384);
        const char* Bc = (const char*)(lds + 32768 + b*16384);
        #pragma unroll
        for(int p = 0; p < 4; ++p){
            half8 aF[2][2], bF[4][2];
            #pragma unroll
            for(int m2 = 0; m2 < 2; m2++){
                int ro = (((wm << 7) + (((p << 1) | m2) << 4) + l15)) << 7;  // row*128B
                aF[m2][0] = *(const half8*)(Ac + ro + xco0);
                aF[m2][1] = *(const half8*)(Ac + ro + xco1);
            }
            #pragma unroll
            for(int nj = 0; nj < 4; nj++){
                int ro = (((wn << 6) + (nj << 4) + l15)) << 7;
                bF[nj][0] = *(const half8*)(Bc + ro + xco0);
                bF[nj][1] = *(const half8*)(Bc + ro + xco1);
            }
            if(p == 3) asm volatile("s_waitcnt lgkmcnt(0)" ::: "memory");  // my reads of buf b done
            __builtin_amdgcn_s_barrier();
            if(p == 3 && it < NT-2){
                // buf b fully consumed by ALL waves -> stage tile it+2 into it
                #pragma unroll
                for(int i = 0; i < 4; i++) stage(b, (it + 2) << 6, i);
            }
            __builtin_amdgcn_s_setprio(1);
            #pragma unroll
            for(int m2 = 0; m2 < 2; m2++)
                #pragma unroll
                for(int nj = 0; nj < 4; nj++){
                    acc[(p<<1)|m2][nj] = __builtin_amdgcn_mfma_f32_16x16x32_f16(aF[m2][0], bF[nj][0], acc[(p<<1)|m2][nj], 0, 0, 0);
                    acc[(p<<1)|m2][nj] = __builtin_amdgcn_mfma_f32_16x16x32_f16(aF[m2][1], bF[nj][1], acc[(p<<1)|m2][nj], 0, 0, 0);
                }
            __builtin_amdgcn_s_setprio(0);
            __builtin_amdgcn_s_barrier();
        }
    }

    int head = (col0 >> 6) + wn;
    float asv[4], adv[4];
    #pragma unroll
    for(int nj = 0; nj < 4; nj++){
        int c = (head << 6) + (nj << 4) + l15;
        asv[nj] = a_s[c]; adv[nj] = a_d[c];
    }
    #pragma unroll
    for(int mi = 0; mi < 8; mi++){
        #pragma unroll
        for(int p2 = 0; p2 < 4; p2++){
            int r = row0 + (wm << 7) + (mi << 4) + (fq << 2) + p2;
            float ps = 0.f, pd = 0.f;
            if(r < M){
                ushort_t* cp = &Cb[(size_t)r*512 + (head << 6) + l15];
                #pragma unroll
                for(int nj = 0; nj < 4; nj++){
                    float v = acc[mi][nj][p2];
                    cp[nj << 4] = f2h(v);
                    ps += v*asv[nj]; pd += v*adv[nj];
                }
            }
            #pragma unroll
            for(int off = 1; off < 16; off <<= 1){
                ps += __shfl_xor(ps, off);
                pd += __shfl_xor(pd, off);
            }
            if(l15 == 0 && r < M){ als[r*8 + head] = ps; ald[r*8 + head] = pd; }
        }
    }
}

// ---------------- edge softmax + aggregation — BARRIER-FREE ----------------
// F2: fuse layer-2 row product via SINGLE-ROW MFMA (no barrier, no LDS, no long
// shuffle-reduce chains — round-3's failure mode avoided): re-gather this wave's
// ELU'd row into the A-frag row 0 via 64 __shfl, B-frags from W2t (16 KB, L1-hot),
// 16 MFMAs -> y[16] on lanes 0-15.  The hbf global store is SKIPPED for F2 (dead).

template<bool F2>
__global__ __launch_bounds__(256) void attn_agg(const ushort_t* __restrict__ h,
        const float* __restrict__ als, const float* __restrict__ ald,
        const int* __restrict__ rowptr, const int* __restrict__ csr,
        const float* __restrict__ bias, ushort_t* __restrict__ out,
        const ushort_t* __restrict__ W2t, const float* __restrict__ a_s2,
        const float* __restrict__ a_d2, float* __restrict__ h2,
        float* __restrict__ als2, float* __restrict__ ald2){
    __shared__ float sex[4][MAXD][8];   // per-edge exp numerators, 8 KB (wave-private slices)
    int wv = threadIdx.x >> 6, lane = threadIdx.x & 63;
    int n = blockIdx.x*4 + wv;
    int start = rowptr[n], end = rowptr[n+1];

    int hd = lane & 7, e8 = lane >> 3;
    float aldv = ald[n*8 + hd];
    float lmax = -1e30f;
    for(int idx = start + e8; idx < end; idx += 8){
        int e = idx - start;
        int src = csr[idx];
        float v = als[src*8 + hd] + aldv;
        v = v > 0.f ? v : NEG*v;
        if(e < MAXD) sex[wv][e][hd] = v;
        lmax = fmaxf(lmax, v);
    }
    for(int off = 8; off < 64; off <<= 1) lmax = fmaxf(lmax, __shfl_xor(lmax, off));
    float lsum = 0.f;
    for(int idx = start + e8; idx < end; idx += 8){
        int e = idx - start;
        float v;
        if(e < MAXD) v = sex[wv][e][hd];
        else { int src = csr[idx]; v = als[src*8 + hd] + aldv; v = v > 0.f ? v : NEG*v; }
        float ex = __expf(v - lmax);
        if(e < MAXD) sex[wv][e][hd] = ex;
        lsum += ex;
    }
    for(int off = 8; off < 64; off <<= 1) lsum += __shfl_xor(lsum, off);

    int head = e8;                       // lane >> 3
    float m_all = __shfl(lmax, head);
    float inv   = 1.f / __shfl(lsum, head);
    float aldn  = __shfl(aldv, head);

    float acc[8] = {};

    int cnt = end - start;
    int nmain = cnt < MAXD ? cnt : MAXD;
    int mend = start + nmain;
    int last = mend - 1;
    for(int idx = start; idx < mend; idx += 8){
        int ss[8]; uint4 pp[8]; float ee[8];
        #pragma unroll
        for(int k = 0; k < 8; k++){
            int j = idx + k;
            ss[k] = csr[j <= last ? j : last];
        }
        #pragma unroll
        for(int k = 0; k < 8; k++)
            pp[k] = *(const uint4*)&h[(size_t)ss[k]*512 + lane*8];
        #pragma unroll
        for(int k = 0; k < 8; k++){
            int j = idx + k;
            ee[k] = (j < mend) ? sex[wv][j-start][head] : 0.f;
        }
        #pragma unroll
        for(int k = 0; k < 8; k++){
            acc[0] += ee[k]*h_lo(pp[k].x); acc[1] += ee[k]*h_hi(pp[k].x);
            acc[2] += ee[k]*h_lo(pp[k].y); acc[3] += ee[k]*h_hi(pp[k].y);
            acc[4] += ee[k]*h_lo(pp[k].z); acc[5] += ee[k]*h_hi(pp[k].z);
            acc[6] += ee[k]*h_lo(pp[k].w); acc[7] += ee[k]*h_hi(pp[k].w);
        }
    }
    if(mend < end){
        for(int idx = mend; idx < end; idx++){
            int src = csr[idx];
            float v = als[src*8 + head] + aldn;
            v = v > 0.f ? v : NEG*v;
            float e0 = __expf(v - m_all);
            uint4 p = *(const uint4*)&h[(size_t)src*512 + lane*8];
            acc[0] += e0*h_lo(p.x); acc[1] += e0*h_hi(p.x);
            acc[2] += e0*h_lo(p.y); acc[3] += e0*h_hi(p.y);
            acc[4] += e0*h_lo(p.z); acc[5] += e0*h_hi(p.z);
            acc[6] += e0*h_lo(p.w); acc[7] += e0*h_hi(p.w);
        }
    }

    ushort8 o;
    #pragma unroll
    for(int j = 0; j < 8; j++){
        float v = acc[j]*inv + bias[lane*8 + j];
        v = v > 0.f ? v : (__expf(v) - 1.f);   // ELU
        o[j] = f2h(v);
    }
    if constexpr (!F2){
        *(ushort8*)&out[(size_t)n*512 + lane*8] = o;
    } else {
        // ---- fused layer 2: y[c] = row . W2[:,c] via single-row MFMA ----
        union { ushort8 v; uint4 d; } ou; ou.v = o;
        int fm2 = lane & 15, fq2 = lane >> 4;
        f32x4 y4 = {};
        #pragma unroll
        for(int kt = 0; kt < 16; kt++){
            int srcl = kt*4 + fq2;                 // lane holding features [kt*32+fq2*8, +8)
            uint4 g;
            g.x = __shfl((int)ou.d.x, srcl); g.y = __shfl((int)ou.d.y, srcl);
            g.z = __shfl((int)ou.d.z, srcl); g.w = __shfl((int)ou.d.w, srcl);
            half8 a = {};
            if(fm2 == 0) a = *(half8*)&g;          // A row 0 = this node's features; rows 1-15 zero
            half8 b = *(const half8*)&W2t[(size_t)fm2*512 + kt*32 + fq2*8];
            y4 = __builtin_amdgcn_mfma_f32_16x16x32_f16(a, b, y4, 0, 0, 0);
        }
        // C row 0 lives on lanes 0-15 (col = lane), reg 0
        float y = y4[0];
        float ps = y * a_s2[fm2], pd = y * a_d2[fm2];
        #pragma unroll
        for(int off = 1; off < 16; off <<= 1){
            ps += __shfl_xor(ps, off);
            pd += __shfl_xor(pd, off);
        }
        if(fq2 == 0){
            h2[(size_t)n*16 + fm2] = y;
            if(fm2 == 0){ als2[n] = ps; ald2[n] = pd; }
        }
    }
}

// final layer agg: 16 lanes per node, 4 nodes per wave, 16 nodes per block.
__global__ __launch_bounds__(256) void attn_agg2(const float* __restrict__ h2,
        const float* __restrict__ als, const float* __restrict__ ald,
        const int* __restrict__ rowptr, const int* __restrict__ csr,
        const float* __restrict__ b2, float* __restrict__ out){
    __shared__ float sex2[16][MAXD+1];   // +1 pad: kill 4-way bank conflict on broadcast reads
    int wv = threadIdx.x >> 6, lane = threadIdx.x & 63;
    int q = lane >> 4, c = lane & 15;
    int slot = wv*4 + q;
    int n = blockIdx.x*16 + slot;
    int start = rowptr[n], end = rowptr[n+1];
    float aldv = ald[n];
    int cnt = end - start;
    int nmain = cnt < MAXD ? cnt : MAXD;
    int mend = start + nmain;

    float lmax = -1e30f;
    for(int idx = start + c; idx < end; idx += 16){
        int e = idx - start;
        float v = als[csr[idx]] + aldv; v = v > 0.f ? v : NEG*v;
        if(e < MAXD) sex2[slot][e] = v;
        lmax = fmaxf(lmax, v);
    }
    #pragma unroll
    for(int off = 1; off < 16; off <<= 1) lmax = fmaxf(lmax, __shfl_xor(lmax, off));
    float lsum = 0.f;
    for(int idx = start + c; idx < end; idx += 16){
        int e = idx - start;
        float v;
        if(e < MAXD) v = sex2[slot][e];
        else { v = als[csr[idx]] + aldv; v = v > 0.f ? v : NEG*v; }
        float ex = __expf(v - lmax);
        if(e < MAXD) sex2[slot][e] = ex;
        lsum += ex;
    }
    #pragma unroll
    for(int off = 1; off < 16; off <<= 1) lsum += __shfl_xor(lsum, off);
    float inv = 1.f / lsum;

    float acc = 0.f;
    for(int idx = start; idx < mend; idx++){
        int src = csr[idx];
        float ex = sex2[slot][idx - start];
        acc += ex * h2[(size_t)src*16 + c];
    }
    for(int idx = mend; idx < end; idx++){
        int src = csr[idx];
        float v = als[src] + aldv; v = v > 0.f ? v : NEG*v;
        acc += __expf(v - lmax) * h2[(size_t)src*16 + c];
    }
    out[(size_t)n*16 + c] = acc*inv + b2[c];
}

// ---------------- launch ----------------

extern "C" void kernel_launch(void* const* d_in, const int* in_sizes, int n_in,
                              void* d_out, int out_size, void* d_ws, size_t ws_size,
                              hipStream_t stream) {
    const float* x    = (const float*)d_in[0];
    const int*   ei   = (const int*)  d_in[1];
    const float* W0   = (const float*)d_in[2];
    const float* a_s0 = (const float*)d_in[3];
    const float* a_d0 = (const float*)d_in[4];
    const float* b0   = (const float*)d_in[5];
    const float* W1   = (const float*)d_in[6];
    const float* a_s1 = (const float*)d_in[7];
    const float* a_d1 = (const float*)d_in[8];
    const float* b1   = (const float*)d_in[9];
    const float* W2   = (const float*)d_in[10];
    const float* a_s2 = (const float*)d_in[11];
    const float* a_d2 = (const float*)d_in[12];
    const float* b2   = (const float*)d_in[13];
    float* out = (float*)d_out;

    char* w = (char*)d_ws;
    auto alloc = [&](size_t bytes){ void* p = (void*)w; w += (bytes + 255) & ~(size_t)255; return p; };
    int*      rowptr = (int*)     alloc((N_NODES+1)*sizeof(int));
    int*      wofs   = (int*)     alloc((N_NODES+1)*sizeof(int));
    int*      bsum   = (int*)     alloc(NB_SCAN*sizeof(int));
    int*      csr    = (int*)     alloc(E_TOT*sizeof(int));
    float*    als    = (float*)   alloc((size_t)N_NODES*8*sizeof(float));
    float*    ald    = (float*)   alloc((size_t)N_NODES*8*sizeof(float));
    float*    als2   = (float*)   alloc((size_t)N_NODES*sizeof(float));
    float*    ald2   = (float*)   alloc((size_t)N_NODES*sizeof(float));
    ushort_t* hb     = (ushort_t*)alloc((size_t)N_NODES*512*sizeof(ushort_t));
    ushort_t* hbf    = (ushort_t*)alloc((size_t)N_NODES*512*sizeof(ushort_t));
    ushort_t* W0t    = (ushort_t*)alloc((size_t)512*128*sizeof(ushort_t));
    ushort_t* W1t    = (ushort_t*)alloc((size_t)512*512*sizeof(ushort_t));
    ushort_t* W2t    = (ushort_t*)alloc((size_t)16*512*sizeof(ushort_t));
    float*    h2     = (float*)   alloc((size_t)N_NODES*16*sizeof(float));

    const int NBLK = 2 * ((N_NODES + 255) / 256);   // 392 workgroups for the 256^2 GEMM

    // dynamic-LDS caps (host-side attrs; capture-safe)
    (void)hipFuncSetAttribute((const void*)gemm_bt8<512>,
                              hipFuncAttributeMaxDynamicSharedMemorySize, 131072);
    (void)hipFuncSetAttribute((const void*)gemm0fs,
                              hipFuncAttributeMaxDynamicSharedMemorySize, 163840);

    // zero deg, then weight conversions + degree count (1 dispatch)
    hipMemsetAsync(wofs, 0, (N_NODES+1)*sizeof(int), stream);
    cvt_all<<<(E_TOT+255)/256, 256, 0, stream>>>(W0, W1, W2, ei, W0t, W1t, W2t, wofs);

    // ordered CSR build: block sums -> fused scan+apply (scatter lives inside gemm0fs)
    deg_block_sum<<<NB_SCAN, 256, 0, stream>>>(wofs, bsum);
    scan_apply<<<NB_SCAN, 256, 0, stream>>>(bsum, wofs, rowptr);

    // layer 0: fused {edge scatter + whole-B LDS-resident GEMM}, logits fused
    gemm0fs<<<NG0, 512, 163840, stream>>>(ei, wofs, csr, x, W0t, hb, a_s0, a_d0, als, ald, N_NODES);
    attn_agg<false><<<N_NODES/4, 256, 0, stream>>>(hb, als, ald, rowptr, csr, b0, hbf,
                                                   nullptr, nullptr, nullptr, nullptr, nullptr, nullptr);

    // layer 1 (256^2 pipelined GEMM + XCD swizzle + counted vmcnt, logits fused);
    // attn layer-1 fuses the layer-2 row product (hbf store skipped — dead)
    gemm_bt8<512><<<NBLK, 512, 131072, stream>>>(hbf, W1t, hb, a_s1, a_d1, als, ald, N_NODES);
    attn_agg<true><<<N_NODES/4, 256, 0, stream>>>(hb, als, ald, rowptr, csr, b1, nullptr,
                                                  W2t, a_s2, a_d2, h2, als2, ald2);

    // final aggregation
    attn_agg2<<<N_NODES/16, 256, 0, stream>>>(h2, als2, ald2, rowptr, csr, b2, out);
}

// Round 11
// 405.843 us; speedup vs baseline: 1.1087x; 1.1087x over previous
//
#include <hip/hip_runtime.h>

#define N_NODES 50000
#define N_EDGES 400000
#define E_TOT   450000   // + self loops
#define NEG 0.2f
#define NB_SCAN ((N_NODES + 255) / 256)   // 196 blocks
#define MAXD 64                            // LDS-cached edges per node (P(deg>64) ~ 0)
#define NG0 196                            // gemm0fs blocks (256 rows each; <= 256 CUs = 1 round)
#define EPB ((E_TOT + NG0 - 1) / NG0)      // edges scattered per gemm0fs block

typedef unsigned short ushort_t;
typedef __attribute__((ext_vector_type(8))) _Float16 half8;  // MFMA A/B frag (4 VGPRs)
typedef __attribute__((ext_vector_type(4))) float  f32x4;    // MFMA C/D frag
typedef __attribute__((ext_vector_type(8))) unsigned short ushort8;

__device__ __forceinline__ ushort_t f2h(float f){
    _Float16 h = (_Float16)f;
    union { _Float16 h; ushort_t u; } v; v.h = h; return v.u;
}
__device__ __forceinline__ float h_lo(unsigned u){
    union { unsigned u; _Float16 h[2]; } v; v.u = u; return (float)v.h[0];
}
__device__ __forceinline__ float h_hi(unsigned u){
    union { unsigned u; _Float16 h[2]; } v; v.u = u; return (float)v.h[1];
}
__device__ __forceinline__ void gload_lds16(const void* g, void* l){
    __builtin_amdgcn_global_load_lds((const __attribute__((address_space(1))) void*)g,
                                     (__attribute__((address_space(3))) void*)l, 16, 0, 0);
}
__device__ __forceinline__ int wave_incl_scan(int v, int lane){
    #pragma unroll
    for(int off = 1; off < 64; off <<= 1){
        int t = __shfl_up(v, off, 64);
        if(lane >= off) v += t;
    }
    return v;
}

// ---------------- fused fp32 -> f16 weight conversions + degree count ----------------
// requires deg (=wofs) pre-zeroed via hipMemsetAsync.  x is staged directly by gemm0fs.

__global__ void cvt_all(const float* __restrict__ W0,
                        const float* __restrict__ W1, const float* __restrict__ W2,
                        const int* __restrict__ ei,
                        ushort_t* __restrict__ W0t,
                        ushort_t* __restrict__ W1t, ushort_t* __restrict__ W2t,
                        int* __restrict__ deg){
    int i = blockIdx.x*256 + threadIdx.x;
    if(i < 512*128){ int n = i >> 7, k = i & 127; W0t[i] = f2h(W0[(size_t)k*512 + n]); }
    if(i < 512*512){ int n = i >> 9, k = i & 511; W1t[i] = f2h(W1[(size_t)k*512 + n]); }
    if(i < 16*512){ int n = i >> 9, k = i & 511; W2t[i] = f2h(W2[(size_t)k*16 + n]); }
    if(i < E_TOT){
        int dst = (i < N_EDGES) ? ei[N_EDGES + i] : (i - N_EDGES);
        atomicAdd(&deg[dst], 1);
    }
}

// ---------------- ordered CSR build: block sums -> fused scan+apply ----------------

__global__ void deg_block_sum(const int* __restrict__ deg, int* __restrict__ bsum){
    int i = blockIdx.x*256 + threadIdx.x;
    int lane = threadIdx.x & 63, wave = threadIdx.x >> 6;
    int v = (i < N_NODES) ? deg[i] : 0;
    #pragma unroll
    for(int off = 1; off < 64; off <<= 1) v += __shfl_xor(v, off, 64);
    __shared__ int sw[4];
    if(lane == 0) sw[wave] = v;
    __syncthreads();
    if(threadIdx.x == 0) bsum[blockIdx.x] = sw[0] + sw[1] + sw[2] + sw[3];
}

__global__ void scan_apply(const int* __restrict__ bsum,
                           int* __restrict__ dw, int* __restrict__ rowptr){
    __shared__ int soff;
    __shared__ int sw[4];
    int i = blockIdx.x*256 + threadIdx.x;
    int lane = threadIdx.x & 63, wave = threadIdx.x >> 6;
    if(wave == 0){
        int s = 0;
        for(int j = lane; j < (int)blockIdx.x; j += 64) s += bsum[j];
        #pragma unroll
        for(int off = 1; off < 64; off <<= 1) s += __shfl_xor(s, off, 64);
        if(lane == 0) soff = s;
    }
    int v = (i < N_NODES) ? dw[i] : 0;
    int incl = wave_incl_scan(v, lane);
    if(lane == 63) sw[wave] = incl;
    __syncthreads();
    int add = soff;
    for(int w = 0; w < wave; w++) add += sw[w];
    int excl = incl - v + add;
    if(i < N_NODES){ rowptr[i] = excl; dw[i] = excl; }
    if(i == N_NODES-1) rowptr[N_NODES] = excl + v;
}

// ---------------- layer-0 GEMM + fused edge scatter (round-9 proven form) ----------------

__global__ __launch_bounds__(512, 1) void gemm0fs(const int* __restrict__ ei,
                                                  int* __restrict__ wofs,
                                                  int* __restrict__ csr,
                                                  const float* __restrict__ x,
                                                  const ushort_t* __restrict__ W0t,
                                                  ushort_t* __restrict__ Cb,
                                                  const float* __restrict__ a_s,
                                                  const float* __restrict__ a_d,
                                                  float* __restrict__ als,
                                                  float* __restrict__ ald, int M){
    extern __shared__ ushort_t lds[];        // Bs: [0,65536) halves, As: [65536,81920)
    ushort_t* Bs = lds;
    ushort_t* As = lds + 512*128;
    int tid = threadIdx.x, wave = tid >> 6, lane = tid & 63;
    int rsub = lane >> 4, c16 = lane & 15;
    int fm = lane & 15, fq = lane >> 4;
    long row0 = (long)blockIdx.x * 256;

    auto stageA = [&](long base){
        #pragma unroll
        for(int t = 0; t < 4; t++){
            int rl = wave*16 + t*4 + rsub;         // local row 0..127
            long gr = base + rl; gr = gr < M ? gr : M-1;
            const float* ap = x + gr*128 + c16*8;
            f32x4 lo = *(const f32x4*)ap;
            f32x4 hi = *(const f32x4*)(ap + 4);
            union { _Float16 h[8]; half8 v; } u;
            u.h[0] = (_Float16)lo[0]; u.h[1] = (_Float16)lo[1];
            u.h[2] = (_Float16)lo[2]; u.h[3] = (_Float16)lo[3];
            u.h[4] = (_Float16)hi[0]; u.h[5] = (_Float16)hi[1];
            u.h[6] = (_Float16)hi[2]; u.h[7] = (_Float16)hi[3];
            *(half8*)&As[(size_t)rl*128 + (c16 ^ (rl & 7))*8] = u.v;
        }
    };
    auto compute = [&](f32x4 (&acc)[8][4]){
        #pragma unroll
        for(int kt = 0; kt < 4; kt++){
            half8 a[8], b[4];
            #pragma unroll
            for(int mi = 0; mi < 8; mi++){
                int r = mi*16 + fm;
                a[mi] = *(const half8*)&As[(size_t)r*128 + ((kt*4 + fq) ^ (r & 7))*8];
            }
            #pragma unroll
            for(int nj = 0; nj < 4; nj++){
                int r = wave*64 + nj*16 + fm;
                b[nj] = *(const half8*)&Bs[(size_t)r*128 + ((kt*4 + fq) ^ (r & 7))*8];
            }
            #pragma unroll
            for(int mi = 0; mi < 8; mi++)
                #pragma unroll
                for(int nj = 0; nj < 4; nj++)
                    acc[mi][nj] = __builtin_amdgcn_mfma_f32_16x16x32_f16(a[mi], b[nj], acc[mi][nj], 0, 0, 0);
        }
    };
    auto epilogue = [&](f32x4 (&acc)[8][4], long base){
        int head = wave;
        float asv[4], adv[4];
        #pragma unroll
        for(int nj = 0; nj < 4; nj++){
            int c = head*64 + nj*16 + fm;
            asv[nj] = a_s[c]; adv[nj] = a_d[c];
        }
        #pragma unroll
        for(int mi = 0; mi < 8; mi++){
            #pragma unroll
            for(int p2 = 0; p2 < 4; p2++){
                long r = base + mi*16 + fq*4 + p2;
                float ps = 0.f, pd = 0.f;
                if(r < M){
                    ushort_t* cp = &Cb[(size_t)r*512 + head*64 + fm];
                    #pragma unroll
                    for(int nj = 0; nj < 4; nj++){
                        float v = acc[mi][nj][p2];
                        cp[nj*16] = f2h(v);
                        ps += v*asv[nj]; pd += v*adv[nj];
                    }
                }
                #pragma unroll
                for(int off = 1; off < 16; off <<= 1){
                    ps += __shfl_xor(ps, off);
                    pd += __shfl_xor(pd, off);
                }
                if(fm == 0 && r < M){ als[r*8 + head] = ps; ald[r*8 + head] = pd; }
            }
        }
    };

    // ---- stage B (whole W0t) + A tile 0 ----
    #pragma unroll
    for(int s = 0; s < 16; s++){
        int rowq = wave*64 + s*4;
        int r = rowq + rsub;
        int sc = c16 ^ (r & 7);
        gload_lds16(W0t + (size_t)r*128 + sc*8, Bs + rowq*128);
    }
    stageA(row0);

    // ---- CSR scatter slice: independent work hiding under staging latency ----
    {
        int e1 = blockIdx.x*EPB + EPB; if(e1 > E_TOT) e1 = E_TOT;
        for(int e = blockIdx.x*EPB + tid; e < e1; e += 512){
            int src, dst;
            if(e < N_EDGES){ src = ei[e]; dst = ei[N_EDGES + e]; }
            else { src = dst = e - N_EDGES; }
            int pos = atomicAdd(&wofs[dst], 1);
            csr[pos] = src;
        }
    }

    __syncthreads();   // drains B gloads + A ds_writes (+ scatter)

    f32x4 acc[8][4] = {};
    compute(acc);
    __syncthreads();            // all waves done reading As (tile 0)
    stageA(row0 + 128);         // tile-1 A-stage issued early...
    epilogue(acc, row0);        // ...hides under tile-0 epilogue stores
    __syncthreads();            // tile-1 As visible

    f32x4 acc2[8][4] = {};
    compute(acc2);
    epilogue(acc2, row0 + 128);
}

// ---------------- layer-1 GEMM: 256x256 tile, BK=64, 8 waves, pipelined + XCD swizzle ----------------
// T4 counted-vmcnt (round-8 proven form).

template<int K>
__global__ __launch_bounds__(512, 2) void gemm_bt8(const ushort_t* __restrict__ A,
                                                   const ushort_t* __restrict__ Bt,
                                                   ushort_t* __restrict__ Cb,
                                                   const float* __restrict__ a_s,
                                                   const float* __restrict__ a_d,
                                                   float* __restrict__ als,
                                                   float* __restrict__ ald, int M){
    extern __shared__ ushort_t lds[];   // As[2]:[0,32768) halves, Bs[2]:[32768,65536) halves = 128 KiB
    constexpr int NT = K / 64;
    int tid = threadIdx.x, wave = tid >> 6, lane = tid & 63;
    int wm = wave >> 2, wn = wave & 3;          // 2M x 4N waves, per-wave C = 128x64

    // bijective XCD remap: both column-halves of a 256-row panel on the same XCD
    int s = blockIdx.x, nb = gridDim.x;
    int cc = s & 7, kk = s >> 3;
    int q = nb >> 3, rr = nb & 7;
    int t = (cc < rr ? cc*(q+1) : rr*(q+1) + (cc-rr)*q) + kk;
    int row0 = (t >> 1) * 256;
    int col0 = (t & 1) * 256;

    int lr = lane >> 3;                 // 0..7
    int cs8 = ((lane & 7) ^ lr) << 3;   // pre-swizzled 8-half chunk offset in source row
    int arows[4], brows[4];
    #pragma unroll
    for(int i = 0; i < 4; i++){
        int r = row0 + (wave << 5) + (i << 3) + lr;
        arows[i] = r < M ? r : M-1;
        brows[i] = col0 + (wave << 5) + (i << 3) + lr;
    }

    int l15 = lane & 15, fq = lane >> 4;
    int xr = (lane & 7) << 4;
    int xco0 = ((fq << 4)      ) ^ xr;  // kstep 0 byte offset within row (swizzled)
    int xco1 = (64 | (fq << 4)) ^ xr;   // kstep 1

    f32x4 acc[8][4] = {};

    auto stage = [&](int nbuf, int kt, int i){
        ushort_t* la = lds + nbuf*16384 + (wave << 11) + (i << 9);
        ushort_t* lb = lds + 32768 + nbuf*16384 + (wave << 11) + (i << 9);
        gload_lds16(A  + (size_t)arows[i]*K + kt + cs8, la);
        gload_lds16(Bt + (size_t)brows[i]*K + kt + cs8, lb);
    };

    // prologue: tile 0 -> buf 0, tile 1 -> buf 1 (16 loads in flight)
    #pragma unroll
    for(int i = 0; i < 4; i++) stage(0, 0, i);
    #pragma unroll
    for(int i = 0; i < 4; i++) stage(1, 64, i);

    for(int it = 0; it < NT; ++it){
        int b = it & 1;
        if(it < NT-1) asm volatile("s_waitcnt vmcnt(8)" ::: "memory");  // tile it done, it+1 in flight
        else         asm volatile("s_waitcnt vmcnt(0)" ::: "memory");
        __builtin_amdgcn_s_barrier();
        const char* Ac = (const char*)(lds + b*16384);
        const char* Bc = (const char*)(lds + 32768 + b*16384);
        #pragma unroll
        for(int p = 0; p < 4; ++p){
            half8 aF[2][2], bF[4][2];
            #pragma unroll
            for(int m2 = 0; m2 < 2; m2++){
                int ro = (((wm << 7) + (((p << 1) | m2) << 4) + l15)) << 7;  // row*128B
                aF[m2][0] = *(const half8*)(Ac + ro + xco0);
                aF[m2][1] = *(const half8*)(Ac + ro + xco1);
            }
            #pragma unroll
            for(int nj = 0; nj < 4; nj++){
                int ro = (((wn << 6) + (nj << 4) + l15)) << 7;
                bF[nj][0] = *(const half8*)(Bc + ro + xco0);
                bF[nj][1] = *(const half8*)(Bc + ro + xco1);
            }
            if(p == 3) asm volatile("s_waitcnt lgkmcnt(0)" ::: "memory");  // my reads of buf b done
            __builtin_amdgcn_s_barrier();
            if(p == 3 && it < NT-2){
                // buf b fully consumed by ALL waves -> stage tile it+2 into it
                #pragma unroll
                for(int i = 0; i < 4; i++) stage(b, (it + 2) << 6, i);
            }
            __builtin_amdgcn_s_setprio(1);
            #pragma unroll
            for(int m2 = 0; m2 < 2; m2++)
                #pragma unroll
                for(int nj = 0; nj < 4; nj++){
                    acc[(p<<1)|m2][nj] = __builtin_amdgcn_mfma_f32_16x16x32_f16(aF[m2][0], bF[nj][0], acc[(p<<1)|m2][nj], 0, 0, 0);
                    acc[(p<<1)|m2][nj] = __builtin_amdgcn_mfma_f32_16x16x32_f16(aF[m2][1], bF[nj][1], acc[(p<<1)|m2][nj], 0, 0, 0);
                }
            __builtin_amdgcn_s_setprio(0);
            __builtin_amdgcn_s_barrier();
        }
    }

    int head = (col0 >> 6) + wn;
    float asv[4], adv[4];
    #pragma unroll
    for(int nj = 0; nj < 4; nj++){
        int c = (head << 6) + (nj << 4) + l15;
        asv[nj] = a_s[c]; adv[nj] = a_d[c];
    }
    #pragma unroll
    for(int mi = 0; mi < 8; mi++){
        #pragma unroll
        for(int p2 = 0; p2 < 4; p2++){
            int r = row0 + (wm << 7) + (mi << 4) + (fq << 2) + p2;
            float ps = 0.f, pd = 0.f;
            if(r < M){
                ushort_t* cp = &Cb[(size_t)r*512 + (head << 6) + l15];
                #pragma unroll
                for(int nj = 0; nj < 4; nj++){
                    float v = acc[mi][nj][p2];
                    cp[nj << 4] = f2h(v);
                    ps += v*asv[nj]; pd += v*adv[nj];
                }
            }
            #pragma unroll
            for(int off = 1; off < 16; off <<= 1){
                ps += __shfl_xor(ps, off);
                pd += __shfl_xor(pd, off);
            }
            if(l15 == 0 && r < M){ als[r*8 + head] = ps; ald[r*8 + head] = pd; }
        }
    }
}

// ---------------- edge softmax + aggregation — BARRIER-FREE ----------------
// F2: fuse layer-2 row product via per-lane partials + REDUCE-SCATTER shuffles
// (no MFMA chain — round-10's failure mode; no 6-deep full-wave chains — round-3's).
// Lane computes p[c] from its 8 features (128 fma_mix); fold lane bits 5..2 with
// keep/send selects (compile-time indices, rule 20 safe); final xor1/xor2 folds.
// Lane l ends with y for c=(l>>2)&15.  hbf store skipped (dead).

template<bool F2>
__global__ __launch_bounds__(256) void attn_agg(const ushort_t* __restrict__ h,
        const float* __restrict__ als, const float* __restrict__ ald,
        const int* __restrict__ rowptr, const int* __restrict__ csr,
        const float* __restrict__ bias, ushort_t* __restrict__ out,
        const ushort_t* __restrict__ W2t, const float* __restrict__ a_s2,
        const float* __restrict__ a_d2, float* __restrict__ h2,
        float* __restrict__ als2, float* __restrict__ ald2){
    __shared__ float sex[4][MAXD][8];   // per-edge exp numerators, 8 KB (wave-private slices)
    int wv = threadIdx.x >> 6, lane = threadIdx.x & 63;
    int n = blockIdx.x*4 + wv;
    int start = rowptr[n], end = rowptr[n+1];

    int hd = lane & 7, e8 = lane >> 3;
    float aldv = ald[n*8 + hd];
    float lmax = -1e30f;
    for(int idx = start + e8; idx < end; idx += 8){
        int e = idx - start;
        int src = csr[idx];
        float v = als[src*8 + hd] + aldv;
        v = v > 0.f ? v : NEG*v;
        if(e < MAXD) sex[wv][e][hd] = v;
        lmax = fmaxf(lmax, v);
    }
    for(int off = 8; off < 64; off <<= 1) lmax = fmaxf(lmax, __shfl_xor(lmax, off));
    float lsum = 0.f;
    for(int idx = start + e8; idx < end; idx += 8){
        int e = idx - start;
        float v;
        if(e < MAXD) v = sex[wv][e][hd];
        else { int src = csr[idx]; v = als[src*8 + hd] + aldv; v = v > 0.f ? v : NEG*v; }
        float ex = __expf(v - lmax);
        if(e < MAXD) sex[wv][e][hd] = ex;
        lsum += ex;
    }
    for(int off = 8; off < 64; off <<= 1) lsum += __shfl_xor(lsum, off);

    int head = e8;                       // lane >> 3
    float m_all = __shfl(lmax, head);
    float inv   = 1.f / __shfl(lsum, head);
    float aldn  = __shfl(aldv, head);

    float acc[8] = {};

    int cnt = end - start;
    int nmain = cnt < MAXD ? cnt : MAXD;
    int mend = start + nmain;
    int last = mend - 1;
    for(int idx = start; idx < mend; idx += 8){
        int ss[8]; uint4 pp[8]; float ee[8];
        #pragma unroll
        for(int k = 0; k < 8; k++){
            int j = idx + k;
            ss[k] = csr[j <= last ? j : last];
        }
        #pragma unroll
        for(int k = 0; k < 8; k++)
            pp[k] = *(const uint4*)&h[(size_t)ss[k]*512 + lane*8];
        #pragma unroll
        for(int k = 0; k < 8; k++){
            int j = idx + k;
            ee[k] = (j < mend) ? sex[wv][j-start][head] : 0.f;
        }
        #pragma unroll
        for(int k = 0; k < 8; k++){
            acc[0] += ee[k]*h_lo(pp[k].x); acc[1] += ee[k]*h_hi(pp[k].x);
            acc[2] += ee[k]*h_lo(pp[k].y); acc[3] += ee[k]*h_hi(pp[k].y);
            acc[4] += ee[k]*h_lo(pp[k].z); acc[5] += ee[k]*h_hi(pp[k].z);
            acc[6] += ee[k]*h_lo(pp[k].w); acc[7] += ee[k]*h_hi(pp[k].w);
        }
    }
    if(mend < end){
        for(int idx = mend; idx < end; idx++){
            int src = csr[idx];
            float v = als[src*8 + head] + aldn;
            v = v > 0.f ? v : NEG*v;
            float e0 = __expf(v - m_all);
            uint4 p = *(const uint4*)&h[(size_t)src*512 + lane*8];
            acc[0] += e0*h_lo(p.x); acc[1] += e0*h_hi(p.x);
            acc[2] += e0*h_lo(p.y); acc[3] += e0*h_hi(p.y);
            acc[4] += e0*h_lo(p.z); acc[5] += e0*h_hi(p.z);
            acc[6] += e0*h_lo(p.w); acc[7] += e0*h_hi(p.w);
        }
    }

    float vv[8];
    ushort8 o;
    #pragma unroll
    for(int j = 0; j < 8; j++){
        float v = acc[j]*inv + bias[lane*8 + j];
        v = v > 0.f ? v : (__expf(v) - 1.f);   // ELU
        vv[j] = v;
        o[j] = f2h(v);
    }
    if constexpr (!F2){
        *(ushort8*)&out[(size_t)n*512 + lane*8] = o;
    } else {
        // ---- per-lane partials: p[c] = vv . W2t[c][lane*8 .. +8) ----
        float p[16];
        const ushort_t* wp = W2t + lane*8;
        #pragma unroll
        for(int c = 0; c < 16; c++){
            uint4 w4 = *(const uint4*)(wp + (size_t)c*512);
            p[c] = vv[0]*h_lo(w4.x) + vv[1]*h_hi(w4.x)
                 + vv[2]*h_lo(w4.y) + vv[3]*h_hi(w4.y)
                 + vv[4]*h_lo(w4.z) + vv[5]*h_hi(w4.z)
                 + vv[6]*h_lo(w4.w) + vv[7]*h_hi(w4.w);
        }
        // ---- reduce-scatter: fold lane bits 5,4,3,2 ----
        bool b5 = (lane & 32);
        float q8[8];
        #pragma unroll
        for(int i = 0; i < 8; i++){
            float keep = b5 ? p[i+8] : p[i];
            float send = b5 ? p[i]   : p[i+8];
            q8[i] = keep + __shfl_xor(send, 32);
        }
        bool b4 = (lane & 16);
        float q4[4];
        #pragma unroll
        for(int i = 0; i < 4; i++){
            float keep = b4 ? q8[i+4] : q8[i];
            float send = b4 ? q8[i]   : q8[i+4];
            q4[i] = keep + __shfl_xor(send, 16);
        }
        bool b3 = (lane & 8);
        float q2[2];
        #pragma unroll
        for(int i = 0; i < 2; i++){
            float keep = b3 ? q4[i+2] : q4[i];
            float send = b3 ? q4[i]   : q4[i+2];
            q2[i] = keep + __shfl_xor(send, 8);
        }
        bool b2 = (lane & 4);
        float keep = b2 ? q2[1] : q2[0];
        float send = b2 ? q2[0] : q2[1];
        float y = keep + __shfl_xor(send, 4);
        // fold remaining lane bits 0,1 (partners hold same c over disjoint lane sets)
        y += __shfl_xor(y, 1);
        y += __shfl_xor(y, 2);
        // lane l now holds full y for c = (l>>2)&15
        int c = (lane >> 2) & 15;
        if((lane & 3) == 0) h2[(size_t)n*16 + c] = y;
        // logits2: lanes l^{4,8,16,32} span all 16 distinct c exactly once
        float ps = y * a_s2[c], pd = y * a_d2[c];
        ps += __shfl_xor(ps, 4);  pd += __shfl_xor(pd, 4);
        ps += __shfl_xor(ps, 8);  pd += __shfl_xor(pd, 8);
        ps += __shfl_xor(ps, 16); pd += __shfl_xor(pd, 16);
        ps += __shfl_xor(ps, 32); pd += __shfl_xor(pd, 32);
        if(lane == 0){ als2[n] = ps; ald2[n] = pd; }
    }
}

// final layer agg: 16 lanes per node, 4 nodes per wave, 16 nodes per block.
__global__ __launch_bounds__(256) void attn_agg2(const float* __restrict__ h2,
        const float* __restrict__ als, const float* __restrict__ ald,
        const int* __restrict__ rowptr, const int* __restrict__ csr,
        const float* __restrict__ b2, float* __restrict__ out){
    __shared__ float sex2[16][MAXD+1];   // +1 pad: kill 4-way bank conflict on broadcast reads
    int wv = threadIdx.x >> 6, lane = threadIdx.x & 63;
    int q = lane >> 4, c = lane & 15;
    int slot = wv*4 + q;
    int n = blockIdx.x*16 + slot;
    int start = rowptr[n], end = rowptr[n+1];
    float aldv = ald[n];
    int cnt = end - start;
    int nmain = cnt < MAXD ? cnt : MAXD;
    int mend = start + nmain;

    float lmax = -1e30f;
    for(int idx = start + c; idx < end; idx += 16){
        int e = idx - start;
        float v = als[csr[idx]] + aldv; v = v > 0.f ? v : NEG*v;
        if(e < MAXD) sex2[slot][e] = v;
        lmax = fmaxf(lmax, v);
    }
    #pragma unroll
    for(int off = 1; off < 16; off <<= 1) lmax = fmaxf(lmax, __shfl_xor(lmax, off));
    float lsum = 0.f;
    for(int idx = start + c; idx < end; idx += 16){
        int e = idx - start;
        float v;
        if(e < MAXD) v = sex2[slot][e];
        else { v = als[csr[idx]] + aldv; v = v > 0.f ? v : NEG*v; }
        float ex = __expf(v - lmax);
        if(e < MAXD) sex2[slot][e] = ex;
        lsum += ex;
    }
    #pragma unroll
    for(int off = 1; off < 16; off <<= 1) lsum += __shfl_xor(lsum, off);
    float inv = 1.f / lsum;

    float acc = 0.f;
    for(int idx = start; idx < mend; idx++){
        int src = csr[idx];
        float ex = sex2[slot][idx - start];
        acc += ex * h2[(size_t)src*16 + c];
    }
    for(int idx = mend; idx < end; idx++){
        int src = csr[idx];
        float v = als[src] + aldv; v = v > 0.f ? v : NEG*v;
        acc += __expf(v - lmax) * h2[(size_t)src*16 + c];
    }
    out[(size_t)n*16 + c] = acc*inv + b2[c];
}

// ---------------- launch ----------------

extern "C" void kernel_launch(void* const* d_in, const int* in_sizes, int n_in,
                              void* d_out, int out_size, void* d_ws, size_t ws_size,
                              hipStream_t stream) {
    const float* x    = (const float*)d_in[0];
    const int*   ei   = (const int*)  d_in[1];
    const float* W0   = (const float*)d_in[2];
    const float* a_s0 = (const float*)d_in[3];
    const float* a_d0 = (const float*)d_in[4];
    const float* b0   = (const float*)d_in[5];
    const float* W1   = (const float*)d_in[6];
    const float* a_s1 = (const float*)d_in[7];
    const float* a_d1 = (const float*)d_in[8];
    const float* b1   = (const float*)d_in[9];
    const float* W2   = (const float*)d_in[10];
    const float* a_s2 = (const float*)d_in[11];
    const float* a_d2 = (const float*)d_in[12];
    const float* b2   = (const float*)d_in[13];
    float* out = (float*)d_out;

    char* w = (char*)d_ws;
    auto alloc = [&](size_t bytes){ void* p = (void*)w; w += (bytes + 255) & ~(size_t)255; return p; };
    int*      rowptr = (int*)     alloc((N_NODES+1)*sizeof(int));
    int*      wofs   = (int*)     alloc((N_NODES+1)*sizeof(int));
    int*      bsum   = (int*)     alloc(NB_SCAN*sizeof(int));
    int*      csr    = (int*)     alloc(E_TOT*sizeof(int));
    float*    als    = (float*)   alloc((size_t)N_NODES*8*sizeof(float));
    float*    ald    = (float*)   alloc((size_t)N_NODES*8*sizeof(float));
    float*    als2   = (float*)   alloc((size_t)N_NODES*sizeof(float));
    float*    ald2   = (float*)   alloc((size_t)N_NODES*sizeof(float));
    ushort_t* hb     = (ushort_t*)alloc((size_t)N_NODES*512*sizeof(ushort_t));
    ushort_t* hbf    = (ushort_t*)alloc((size_t)N_NODES*512*sizeof(ushort_t));
    ushort_t* W0t    = (ushort_t*)alloc((size_t)512*128*sizeof(ushort_t));
    ushort_t* W1t    = (ushort_t*)alloc((size_t)512*512*sizeof(ushort_t));
    ushort_t* W2t    = (ushort_t*)alloc((size_t)16*512*sizeof(ushort_t));
    float*    h2     = (float*)   alloc((size_t)N_NODES*16*sizeof(float));

    const int NBLK = 2 * ((N_NODES + 255) / 256);   // 392 workgroups for the 256^2 GEMM

    // dynamic-LDS caps (host-side attrs; capture-safe)
    (void)hipFuncSetAttribute((const void*)gemm_bt8<512>,
                              hipFuncAttributeMaxDynamicSharedMemorySize, 131072);
    (void)hipFuncSetAttribute((const void*)gemm0fs,
                              hipFuncAttributeMaxDynamicSharedMemorySize, 163840);

    // zero deg, then weight conversions + degree count (1 dispatch)
    hipMemsetAsync(wofs, 0, (N_NODES+1)*sizeof(int), stream);
    cvt_all<<<(E_TOT+255)/256, 256, 0, stream>>>(W0, W1, W2, ei, W0t, W1t, W2t, wofs);

    // ordered CSR build: block sums -> fused scan+apply (scatter lives inside gemm0fs)
    deg_block_sum<<<NB_SCAN, 256, 0, stream>>>(wofs, bsum);
    scan_apply<<<NB_SCAN, 256, 0, stream>>>(bsum, wofs, rowptr);

    // layer 0: fused {edge scatter + whole-B LDS-resident GEMM}, logits fused
    gemm0fs<<<NG0, 512, 163840, stream>>>(ei, wofs, csr, x, W0t, hb, a_s0, a_d0, als, ald, N_NODES);
    attn_agg<false><<<N_NODES/4, 256, 0, stream>>>(hb, als, ald, rowptr, csr, b0, hbf,
                                                   nullptr, nullptr, nullptr, nullptr, nullptr, nullptr);

    // layer 1 (256^2 pipelined GEMM + XCD swizzle + counted vmcnt, logits fused);
    // attn layer-1 fuses the layer-2 row product via reduce-scatter (hbf store dead)
    gemm_bt8<512><<<NBLK, 512, 131072, stream>>>(hbf, W1t, hb, a_s1, a_d1, als, ald, N_NODES);
    attn_agg<true><<<N_NODES/4, 256, 0, stream>>>(hb, als, ald, rowptr, csr, b1, nullptr,
                                                  W2t, a_s2, a_d2, h2, als2, ald2);

    // final aggregation
    attn_agg2<<<N_NODES/16, 256, 0, stream>>>(h2, als2, ald2, rowptr, csr, b2, out);
}